// Round 3
// baseline (178.390 us; speedup 1.0000x reference)
//
#include <hip/hip_runtime.h>

// Problem constants
#define BB 256      // batch
#define CCH 512     // channels
#define HW 196      // 14*14 spatial
#define TT 197      // templates_b rows (196 + 1 negative)
#define TROWS 208   // padded T rows (13 * 16)
#define TBK 224     // padded K for templates (7 * 32)
#define KPAD 232    // X LDS row length in shorts (464B rows, 16B aligned)

typedef __attribute__((ext_vector_type(8))) short bf16x8;
typedef __attribute__((ext_vector_type(4))) float f32x4;
typedef __attribute__((ext_vector_type(4))) unsigned short us4;

__device__ __forceinline__ unsigned short f2bf(float f) {
    union { float f; unsigned u; } v; v.f = f;
    unsigned r = v.u + 0x7FFFu + ((v.u >> 16) & 1u);   // round-to-nearest-even
    return (unsigned short)(r >> 16);
}
__device__ __forceinline__ float bf2f(unsigned short h) {
    union { unsigned u; float f; } v; v.u = ((unsigned)h) << 16;
    return v.f;
}

// ---- prep: gmax = max(templates_f). Every 14x14 window of the 27x27 base
// contains the base's center peak, so max(sel) == max(templates_f).
__global__ void prep_gmax(const float* __restrict__ tf, float* __restrict__ wsf) {
    __shared__ float red[1024];
    float m = -1e30f;
    for (int i = threadIdx.x; i < HW * HW; i += 1024) m = fmaxf(m, tf[i]);
    red[threadIdx.x] = m;
    __syncthreads();
    for (int s = 512; s > 0; s >>= 1) {
        if (threadIdx.x < s) red[threadIdx.x] = fmaxf(red[threadIdx.x], red[threadIdx.x + s]);
        __syncthreads();
    }
    if (threadIdx.x == 0) wsf[0] = red[0];
}

// ---- prep: templates_b * tau -> bf16, zero-padded to 208 x 224
__global__ void prep_tb(const float* __restrict__ tb, unsigned short* __restrict__ tb_bf) {
    int i = blockIdx.x * 256 + threadIdx.x;
    if (i >= TROWS * TBK) return;
    int r = i / TBK, k = i % TBK;
    const float tau = 0.5f / 196.0f;
    float v = (r < TT && k < HW) ? tb[r * HW + k] * tau : 0.0f;
    tb_bf[i] = f2bf(v);
}

// ---- main fused kernel: one workgroup (1024 threads, 16 waves) per channel.
// Stage is two-pass with LDS as the row buffer (no 52-reg retention):
//   pass1: stream x, running argmax, bf16(x) -> LDS
//   pass2: LDS -> mask -> fp32 stores + masked bf16 writeback
// GEMM: wave w owns batch cols w*16..+15, all 13 M-tiles in acc registers.
extern "C" __global__ __launch_bounds__(1024)
void fused_main(const float* __restrict__ x, const float* __restrict__ tf,
                const float* __restrict__ pT, const unsigned short* __restrict__ tb_bf,
                const float* __restrict__ wsf,
                float* __restrict__ xm_out, float* __restrict__ mask_out,
                float* __restrict__ loss_out)
{
    extern __shared__ char smem[];
    unsigned short* X = (unsigned short*)smem;                 // [256][KPAD] bf16
    float* s_part = (float*)(smem + BB * KPAD * 2);            // [16][208] per-wave col sums
    float* rAs    = s_part + 16 * TROWS;                       // [208]
    float* pTs    = rAs + TROWS;                               // [208]
    float* red    = pTs + TROWS;                               // [16]

    const int c    = blockIdx.x;
    const int tid  = threadIdx.x;
    const int lane = tid & 63;
    const int w    = tid >> 6;
    const int l15  = lane & 15, lg = lane >> 4;
    const float rg = 1.0f / wsf[0];

    if (tid < TROWS) pTs[tid] = (tid < TT) ? pT[tid] : 0.0f;

    const int b = tid >> 2;             // 0..255
    const int q = tid & 3;
    const int nch = (q == 0) ? 13 : 12; // q=0 also takes chunk 48

    const size_t rowoff = ((size_t)b * CCH + c) * HW;
    const float* xrow = x + rowoff;
    unsigned short* xr = X + b * KPAD;

    if (q == 0) {   // zero-pad shorts 196..231
        #pragma unroll
        for (int j = 0; j < 9; ++j) {
            us4 z = (us4){0, 0, 0, 0};
            *(us4*)(xr + HW + 4 * j) = z;
        }
    }

    // ---- pass 1: streaming argmax + bf16(x) -> LDS (depth-2 prefetch)
    float bv = -1e30f; int bi = 0;
    f32x4 nxt = *(const f32x4*)(xrow + q * 4);
    #pragma unroll 1
    for (int j = 0; j < 13; ++j) {
        f32x4 cur = nxt;
        if (j + 1 < nch) nxt = *(const f32x4*)(xrow + (q + 4 * (j + 1)) * 4);
        if (j < nch) {
            const int k0 = (q + 4 * j) * 4;
            us4 pk;
            #pragma unroll
            for (int e = 0; e < 4; ++e) {
                float v = cur[e];
                if (v > bv) { bv = v; bi = k0 + e; }   // k ascends per lane -> first max kept
                pk[e] = f2bf(v);
            }
            *(us4*)(xr + k0) = pk;
        }
    }
    #pragma unroll
    for (int m = 1; m <= 2; m <<= 1) {
        float ov = __shfl_xor(bv, m, 64);
        int   oi = __shfl_xor(bi, m, 64);
        if (ov > bv || (ov == bv && oi < bi)) { bv = ov; bi = oi; }
    }

    // ---- pass 2: mask from selected template, stores, masked bf16 writeback
    const float* selrow = tf + (size_t)bi * HW;
    float* xmrow = xm_out + rowoff;
    float* mkrow = mask_out + rowoff;

    f32x4 seln = *(const f32x4*)(selrow + q * 4);
    #pragma unroll 1
    for (int j = 0; j < 13; ++j) {
        f32x4 sel = seln;
        if (j + 1 < nch) seln = *(const f32x4*)(selrow + (q + 4 * (j + 1)) * 4);
        if (j < nch) {
            const int k0 = (q + 4 * j) * 4;
            us4 xb = *(us4*)(xr + k0);
            f32x4 mk, xm; us4 pk;
            #pragma unroll
            for (int e = 0; e < 4; ++e) {
                float m = fmaxf(sel[e] * rg - 0.2f, 0.0f) * 5.0f;
                mk[e] = m;
                xm[e] = bf2f(xb[e]) * m;
                pk[e] = f2bf(xm[e]);
            }
            *(f32x4*)(xmrow + k0) = xm;
            *(f32x4*)(mkrow + k0) = mk;
            *(us4*)(xr + k0) = pk;
        }
    }
    __syncthreads();

    // ---- GEMM: tr[t, b] for this wave's 16 batches, all 208 t in registers.
    f32x4 acc[13];
    #pragma unroll
    for (int mt = 0; mt < 13; ++mt) acc[mt] = (f32x4){0.f, 0.f, 0.f, 0.f};

    const unsigned short* xb2 = X + (w * 16 + l15) * KPAD;
    #pragma unroll 1
    for (int kt = 0; kt < 7; ++kt) {
        const int kb = kt * 32 + lg * 8;
        bf16x8 bfrag = *(const bf16x8*)(xb2 + kb);
        #pragma unroll
        for (int mt = 0; mt < 13; ++mt) {
            bf16x8 afrag = *(const bf16x8*)(tb_bf + (mt * 16 + l15) * TBK + kb);
            acc[mt] = __builtin_amdgcn_mfma_f32_16x16x32_bf16(afrag, bfrag, acc[mt], 0, 0, 0);
        }
    }

    // ---- Phase A: exp in-register, column-sum over this wave's 16 b, cross-wave via LDS
    float* sp = s_part + w * TROWS;
    #pragma unroll
    for (int mt = 0; mt < 13; ++mt) {
        #pragma unroll
        for (int e = 0; e < 4; ++e) acc[mt][e] = __expf(acc[mt][e]);
        f32x4 s = acc[mt];
        #pragma unroll
        for (int m = 1; m <= 8; m <<= 1) {
            #pragma unroll
            for (int e = 0; e < 4; ++e) s[e] += __shfl_xor(s[e], m, 64);
        }
        if (l15 == 0) *(f32x4*)(sp + mt * 16 + lg * 4) = s;
    }
    __syncthreads();
    if (tid < TROWS) {
        float s = 0.f;
        #pragma unroll
        for (int w2 = 0; w2 < 16; ++w2) s += s_part[w2 * TROWS + tid];
        rAs[tid] = 1.0f / s;
    }
    __syncthreads();

    // ---- Phase B: p = exp*rA, px[b] = sum_t pT*p
    float px = 0.f;
    #pragma unroll
    for (int mt = 0; mt < 13; ++mt) {
        const int t0 = mt * 16 + lg * 4;
        f32x4 ra = *(const f32x4*)(rAs + t0);
        f32x4 pt = *(const f32x4*)(pTs + t0);
        #pragma unroll
        for (int e = 0; e < 4; ++e) {
            float p = acc[mt][e] * ra[e];
            acc[mt][e] = p;
            px += pt[e] * p;
        }
    }
    px += __shfl_xor(px, 16, 64);
    px += __shfl_xor(px, 32, 64);
    const float rpx = 1.0f / px;

    // ---- Phase C: loss partial = sum_t pT * p * log(p/px)
    float part = 0.f;
    #pragma unroll
    for (int mt = 0; mt < 13; ++mt) {
        const int t0 = mt * 16 + lg * 4;
        f32x4 pt = *(const f32x4*)(pTs + t0);
        #pragma unroll
        for (int e = 0; e < 4; ++e) {
            float p = acc[mt][e];
            part += pt[e] * p * __logf(p * rpx);
        }
    }
    #pragma unroll
    for (int off = 32; off >= 1; off >>= 1) part += __shfl_xor(part, off, 64);
    if (lane == 0) red[w] = part;
    __syncthreads();
    if (tid == 0) {
        float s = 0.f;
        #pragma unroll
        for (int w2 = 0; w2 < 16; ++w2) s += red[w2];
        loss_out[c] = -s;
    }
}

extern "C" void kernel_launch(void* const* d_in, const int* in_sizes, int n_in,
                              void* d_out, int out_size, void* d_ws, size_t ws_size,
                              hipStream_t stream) {
    const float* x  = (const float*)d_in[0];
    const float* tf = (const float*)d_in[1];
    const float* tb = (const float*)d_in[2];
    const float* pT = (const float*)d_in[3];

    const size_t NOUT = (size_t)BB * CCH * HW;
    float* xm_out = (float*)d_out;
    float* mk_out = xm_out + NOUT;
    float* ls_out = mk_out + NOUT;

    float* wsf = (float*)d_ws;
    unsigned short* tb_bf = (unsigned short*)((char*)d_ws + 64);   // 208*224*2 = 93184 B

    prep_gmax<<<1, 1024, 0, stream>>>(tf, wsf);
    prep_tb<<<(TROWS * TBK + 255) / 256, 256, 0, stream>>>(tb, tb_bf);

    const size_t SMEM = (size_t)BB * KPAD * 2              // X: 118784
                      + 16 * TROWS * 4                     // s_part: 13312
                      + TROWS * 4 + TROWS * 4 + 16 * 4;    // rAs + pTs + red
    hipFuncSetAttribute((const void*)fused_main, hipFuncAttributeMaxDynamicSharedMemorySize, (int)SMEM);
    fused_main<<<dim3(CCH), dim3(1024), SMEM, stream>>>(x, tf, pT, tb_bf, wsf,
                                                        xm_out, mk_out, ls_out);
}